// Round 7
// baseline (677.329 us; speedup 1.0000x reference)
//
#include <hip/hip_runtime.h>
#include <cstddef>
#include <cstdint>

// ---------------------------------------------------------------------------
// JKNet: h1 = relu((D_in^-1/2 A D_out^-1/2 x) @ W1 + b1)
//        h2 = relu((D_in^-1/2 A D_out^-1/2 h1) @ W2 + b2)
//        out = A@(h1@Wo1 + h2@Wo2) + bout   (bout folded into final gather)
// Aggregate-first refactor (SpMM commutes with dense GEMM).
// R3: atomic-free CSR build (LDS histograms; global atomics are memory-side
//     on gfx950, ~40ns each).
// R4: k_agg 4-edge unroll + dual accumulators (2x rows in flight);
//     nontemporal O1 stores (don't evict gather-hot L2 lines with the 51MB
//     streaming accumulator write); RANGE 12800->25600 (ranges 8->4) halves
//     edge-array re-reads in k_hist/k_csr.
// R6: fix compile error — __builtin_nontemporal_store needs a native clang
//     vector type, not HIP_vector_type<float,4>. Store via ext_vector_type.
// ---------------------------------------------------------------------------

#define THREADS 256
#define RANGE 25600      // nodes per LDS histogram slice (100 KB LDS)
#define CHUNKS 32        // edge chunks

typedef float f32x4 __attribute__((ext_vector_type(4)));

__device__ __forceinline__ void nt_store_f4(const float4 s, float4* dst) {
  f32x4 v; v.x = s.x; v.y = s.y; v.z = s.z; v.w = s.w;
  __builtin_nontemporal_store(v, (f32x4*)dst);
}

__device__ __forceinline__ float4 f4_fma(const float4 v, const float w, float4 a) {
  a.x += v.x * w; a.y += v.y * w; a.z += v.z * w; a.w += v.w * w; return a;
}
__device__ __forceinline__ float4 f4_add(const float4 v, float4 a) {
  a.x += v.x; a.y += v.y; a.z += v.z; a.w += v.w; return a;
}

// ---- 2D histogram: hist[c][v] = #edges in chunk c with key==v ---------------
// grid = ranges * CHUNKS * 2; aid picks dst (histD) or src (histS).
__global__ __launch_bounds__(THREADS)
void k_hist(const int* __restrict__ dst, const int* __restrict__ src,
            int* __restrict__ histD, int* __restrict__ histS,
            int N, int E, int ranges) {
  __shared__ int h[RANGE];
  int aid = blockIdx.x & 1;
  int r = (blockIdx.x >> 1) % ranges;
  int c = (blockIdx.x >> 1) / ranges;
  const int* arr = aid ? src : dst;
  int* hist = aid ? histS : histD;
  int lo = r * RANGE;
  unsigned span = (unsigned)min(RANGE, N - lo);
  int t = threadIdx.x;
  for (int j = t; j < RANGE; j += THREADS) h[j] = 0;
  __syncthreads();

  int beg = (int)((long long)c * E / CHUNKS);
  int end = (int)((long long)(c + 1) * E / CHUNKS);
  int a = min(end, (beg + 3) & ~3);
  for (int i = beg + t; i < a; i += THREADS) {
    unsigned u = (unsigned)(arr[i] - lo);
    if (u < span) atomicAdd(&h[u], 1);
  }
  for (int i4 = a + t * 4; i4 + 3 < end; i4 += THREADS * 4) {
    int4 v = *(const int4*)(arr + i4);
    unsigned u0 = (unsigned)(v.x - lo), u1 = (unsigned)(v.y - lo);
    unsigned u2 = (unsigned)(v.z - lo), u3 = (unsigned)(v.w - lo);
    if (u0 < span) atomicAdd(&h[u0], 1);
    if (u1 < span) atomicAdd(&h[u1], 1);
    if (u2 < span) atomicAdd(&h[u2], 1);
    if (u3 < span) atomicAdd(&h[u3], 1);
  }
  int tail = a + ((end - a) & ~3);
  for (int i = tail + t; i < end; i += THREADS) {
    unsigned u = (unsigned)(arr[i] - lo);
    if (u < span) atomicAdd(&h[u], 1);
  }
  __syncthreads();
  for (int j = t; j < (int)span; j += THREADS) hist[(size_t)c * N + lo + j] = h[j];
}

// ---- reduce hist columns -> deg_i, invi, invo ------------------------------
__global__ void k_redinv(const int* __restrict__ histD, const int* __restrict__ histS,
                         int* __restrict__ deg_i, float* __restrict__ inv_in,
                         float* __restrict__ inv_out, int N) {
  int v = blockIdx.x * blockDim.x + threadIdx.x;
  if (v >= N) return;
  int sD = 0, sS = 0;
#pragma unroll
  for (int c = 0; c < CHUNKS; ++c) {
    sD += histD[(size_t)c * N + v];
    sS += histS[(size_t)c * N + v];
  }
  deg_i[v] = sD;
  inv_in[v]  = rsqrtf((float)max(sD, 1));
  inv_out[v] = rsqrtf((float)max(sS, 1));
}

// ---- exclusive scan of deg_i -> row_ptr (3 kernels, chunk=1024) ------------
__global__ void k_scan1(const int* __restrict__ deg, int* __restrict__ incl,
                        int* __restrict__ bsums, int N) {
  __shared__ int sd[1024];
  int base = blockIdx.x * 1024;
  for (int j = threadIdx.x; j < 1024; j += THREADS) sd[j] = (base + j < N) ? deg[base + j] : 0;
  __syncthreads();
  for (int off = 1; off < 1024; off <<= 1) {
    int v[4];
#pragma unroll
    for (int k = 0; k < 4; ++k) { int j = threadIdx.x + k * THREADS; v[k] = (j >= off) ? sd[j - off] : 0; }
    __syncthreads();
#pragma unroll
    for (int k = 0; k < 4; ++k) { int j = threadIdx.x + k * THREADS; sd[j] += v[k]; }
    __syncthreads();
  }
  for (int j = threadIdx.x; j < 1024; j += THREADS) if (base + j < N) incl[base + j] = sd[j];
  if (threadIdx.x == 0) bsums[blockIdx.x] = sd[1023];
}

__global__ void k_scan2(const int* __restrict__ bsums, int* __restrict__ boffs, int nb) {
  __shared__ int sd[256];
  int t = threadIdx.x;
  sd[t] = (t < nb) ? bsums[t] : 0;
  __syncthreads();
  for (int off = 1; off < 256; off <<= 1) {
    int v = (t >= off) ? sd[t - off] : 0;
    __syncthreads();
    sd[t] += v;
    __syncthreads();
  }
  if (t < nb) boffs[t] = (t == 0) ? 0 : sd[t - 1];
}

__global__ void k_scan3(int* __restrict__ incl_rowptr, const int* __restrict__ deg,
                        const int* __restrict__ boffs, int N, int E) {
  int i = blockIdx.x * blockDim.x + threadIdx.x;
  if (i < N) incl_rowptr[i] = incl_rowptr[i] - deg[i] + boffs[i >> 10];
  if (i == 0) incl_rowptr[N] = E;
}

// ---- chunk-scan: histD[c][v] -> scatter offset base row_ptr[v]+prefix ------
__global__ void k_chunkscan(int* __restrict__ histD, const int* __restrict__ row_ptr, int N) {
  int v = blockIdx.x * blockDim.x + threadIdx.x;
  if (v >= N) return;
  int run = row_ptr[v];
#pragma unroll
  for (int c = 0; c < CHUNKS; ++c) {
    size_t idx = (size_t)c * N + v;
    int t = histD[idx];
    histD[idx] = run;
    run += t;
  }
}

// ---- CSR fill: rank via LDS atomic on range slice of offsets ---------------
// grid = ranges * CHUNKS, block (r, c): r = blockIdx % ranges (XCD-affine).
__global__ __launch_bounds__(THREADS)
void k_csr(const int* __restrict__ dst, const int* __restrict__ src,
           const int* __restrict__ offs, int* __restrict__ csr_src,
           int N, int E, int ranges) {
  __shared__ int offL[RANGE];
  int r = blockIdx.x % ranges;
  int c = blockIdx.x / ranges;
  int lo = r * RANGE;
  unsigned span = (unsigned)min(RANGE, N - lo);
  int t = threadIdx.x;
  for (int j = t; j < (int)span; j += THREADS) offL[j] = offs[(size_t)c * N + lo + j];
  __syncthreads();

  int beg = (int)((long long)c * E / CHUNKS);
  int end = (int)((long long)(c + 1) * E / CHUNKS);
  int a = min(end, (beg + 3) & ~3);
  for (int i = beg + t; i < a; i += THREADS) {
    unsigned u = (unsigned)(dst[i] - lo);
    if (u < span) csr_src[atomicAdd(&offL[u], 1)] = src[i];
  }
  for (int i4 = a + t * 4; i4 + 3 < end; i4 += THREADS * 4) {
    int4 d = *(const int4*)(dst + i4);
    int4 s = *(const int4*)(src + i4);
    unsigned u0 = (unsigned)(d.x - lo), u1 = (unsigned)(d.y - lo);
    unsigned u2 = (unsigned)(d.z - lo), u3 = (unsigned)(d.w - lo);
    if (u0 < span) csr_src[atomicAdd(&offL[u0], 1)] = s.x;
    if (u1 < span) csr_src[atomicAdd(&offL[u1], 1)] = s.y;
    if (u2 < span) csr_src[atomicAdd(&offL[u2], 1)] = s.z;
    if (u3 < span) csr_src[atomicAdd(&offL[u3], 1)] = s.w;
  }
  int tail = a + ((end - a) & ~3);
  for (int i = tail + t; i < end; i += THREADS) {
    unsigned u = (unsigned)(dst[i] - lo);
    if (u < span) csr_src[atomicAdd(&offL[u], 1)] = src[i];
  }
}

// ---- CSR aggregation (128-wide): O1[v] = sum_{e:dst=v} H[src]*invout[src] --
// 4-edge unroll, dual accumulators, nontemporal output store.
__global__ __launch_bounds__(THREADS)
void k_agg(const float4* __restrict__ H, const float* __restrict__ inv_out,
           const int* __restrict__ row_ptr, const int* __restrict__ csr_src,
           float4* __restrict__ O1, int N) {
  int g = blockIdx.x * (THREADS / 32) + (threadIdx.x >> 5);
  int lane = threadIdx.x & 31;
  if (g >= N) return;
  int e = row_ptr[g], end = row_ptr[g + 1];
  float4 sa = make_float4(0.f, 0.f, 0.f, 0.f);
  float4 sb = make_float4(0.f, 0.f, 0.f, 0.f);
  for (; e + 3 < end; e += 4) {
    int n0 = csr_src[e], n1 = csr_src[e + 1], n2 = csr_src[e + 2], n3 = csr_src[e + 3];
    float4 v0 = H[(size_t)n0 * 32 + lane];
    float4 v1 = H[(size_t)n1 * 32 + lane];
    float4 v2 = H[(size_t)n2 * 32 + lane];
    float4 v3 = H[(size_t)n3 * 32 + lane];
    float w0 = inv_out[n0], w1 = inv_out[n1], w2 = inv_out[n2], w3 = inv_out[n3];
    sa = f4_fma(v0, w0, sa); sb = f4_fma(v1, w1, sb);
    sa = f4_fma(v2, w2, sa); sb = f4_fma(v3, w3, sb);
  }
  for (; e < end; ++e) {
    int n0 = csr_src[e];
    sa = f4_fma(H[(size_t)n0 * 32 + lane], inv_out[n0], sa);
  }
  float4 s = f4_add(sa, sb);
  nt_store_f4(s, &O1[(size_t)g * 32 + lane]);
}

// ---- CSR aggregation (64-wide, unweighted, +bout): out = sum z[src] + bout -
__global__ __launch_bounds__(THREADS)
void k_agg_z(const float4* __restrict__ Z, const int* __restrict__ row_ptr,
             const int* __restrict__ csr_src, const float* __restrict__ bo,
             float4* __restrict__ Out, int N) {
  int g = blockIdx.x * (THREADS / 16) + (threadIdx.x >> 4);
  int lane = threadIdx.x & 15;
  if (g >= N) return;
  int e = row_ptr[g], end = row_ptr[g + 1];
  float4 sa = ((const float4*)bo)[lane];
  float4 sb = make_float4(0.f, 0.f, 0.f, 0.f);
  for (; e + 3 < end; e += 4) {
    int n0 = csr_src[e], n1 = csr_src[e + 1], n2 = csr_src[e + 2], n3 = csr_src[e + 3];
    float4 v0 = Z[(size_t)n0 * 16 + lane];
    float4 v1 = Z[(size_t)n1 * 16 + lane];
    float4 v2 = Z[(size_t)n2 * 16 + lane];
    float4 v3 = Z[(size_t)n3 * 16 + lane];
    sa = f4_add(v0, sa); sb = f4_add(v1, sb);
    sa = f4_add(v2, sa); sb = f4_add(v3, sb);
  }
  for (; e < end; ++e) sa = f4_add(Z[(size_t)csr_src[e] * 16 + lane], sa);
  float4 s = f4_add(sa, sb);
  nt_store_f4(s, &Out[(size_t)g * 16 + lane]);
}

// ---- 128x128 GEMM, fused scale+bias+relu ----------------------------------
template <bool RELU>
__global__ __launch_bounds__(THREADS, 2)
void k_gemm128(const float* __restrict__ A, const float* __restrict__ W,
               const float* __restrict__ bias, const float* __restrict__ scale,
               float* __restrict__ Out, int N) {
  __shared__ float As[2][32 * 132];   // transposed: As[k][row], stride 132
  __shared__ float Ws[2][32 * 128];   // Ws[k][col]
  int t = threadIdx.x;
  int row0 = blockIdx.x * 128;
  int tx = t & 15, ty = t >> 4;
  int c0 = tx * 8, r0 = ty * 8;

  const float4* Av = (const float4*)A;
  const float4* Wv = (const float4*)W;

  float4 la[4], lw[4];
  auto stage_load = [&](int chunk) {
#pragma unroll
    for (int j = 0; j < 4; ++j) {
      int i = t + j * 256;
      int r = i >> 3, kq = i & 7;
      la[j] = make_float4(0.f, 0.f, 0.f, 0.f);
      int gr = row0 + r;
      if (gr < N) la[j] = Av[(size_t)gr * 32 + chunk * 8 + kq];
    }
#pragma unroll
    for (int j = 0; j < 4; ++j) {
      int i = t + j * 256;
      lw[j] = Wv[(size_t)(chunk * 32 + (i >> 5)) * 32 + (i & 31)];
    }
  };
  auto stage_write = [&](int buf) {
#pragma unroll
    for (int j = 0; j < 4; ++j) {
      int i = t + j * 256;
      int r = i >> 3, kq = i & 7;
      float* p = As[buf] + kq * 4 * 132 + r;
      p[0] = la[j].x; p[132] = la[j].y; p[264] = la[j].z; p[396] = la[j].w;
    }
    float4* Wsv = (float4*)Ws[buf];
#pragma unroll
    for (int j = 0; j < 4; ++j) Wsv[t + j * 256] = lw[j];
  };

  float acc[8][8] = {};
  stage_load(0);
  stage_write(0);
#pragma unroll 1
  for (int c = 0; c < 4; ++c) {
    __syncthreads();
    if (c < 3) stage_load(c + 1);
    const float* At = As[c & 1];
    const float* Wc = Ws[c & 1];
#pragma unroll 4
    for (int k = 0; k < 32; ++k) {
      float4 a0 = *(const float4*)&At[k * 132 + r0];
      float4 a1 = *(const float4*)&At[k * 132 + r0 + 4];
      float4 w0 = *(const float4*)&Wc[k * 128 + c0];
      float4 w1 = *(const float4*)&Wc[k * 128 + c0 + 4];
      float av[8] = {a0.x, a0.y, a0.z, a0.w, a1.x, a1.y, a1.z, a1.w};
      float wv[8] = {w0.x, w0.y, w0.z, w0.w, w1.x, w1.y, w1.z, w1.w};
#pragma unroll
      for (int ii = 0; ii < 8; ++ii)
#pragma unroll
        for (int jj = 0; jj < 8; ++jj)
          acc[ii][jj] += av[ii] * wv[jj];
    }
    if (c < 3) stage_write((c + 1) & 1);
  }

  float bj[8];
#pragma unroll
  for (int j = 0; j < 8; ++j) bj[j] = bias[c0 + j];
#pragma unroll
  for (int i = 0; i < 8; ++i) {
    int r = row0 + r0 + i;
    if (r < N) {
      float s = scale[r];
      float o[8];
#pragma unroll
      for (int j = 0; j < 8; ++j) {
        float v = acc[i][j] * s + bj[j];
        o[j] = RELU ? fmaxf(v, 0.f) : v;
      }
      float4* op = (float4*)Out + (size_t)r * 32 + (c0 >> 2);
      op[0] = make_float4(o[0], o[1], o[2], o[3]);
      op[1] = make_float4(o[4], o[5], o[6], o[7]);
    }
  }
}

// ---- z GEMM: Z = A3 @ Wo[0:128] + A4 @ Wo[128:256]  (N x 64) ---------------
__global__ __launch_bounds__(THREADS, 3)
void k_gemm_z(const float* __restrict__ A3, const float* __restrict__ A4,
              const float* __restrict__ Wo, float* __restrict__ Out, int N) {
  __shared__ float As[2][32 * 132];
  __shared__ float Ws[2][32 * 64];
  int t = threadIdx.x;
  int row0 = blockIdx.x * 128;
  int tx = t & 15, ty = t >> 4;
  int c0 = tx * 4, r0 = ty * 8;

  const float4* Wv = (const float4*)Wo;

  float4 la[4], lw[2];
  auto stage_load = [&](int chunk) {
    const float4* Av = (const float4*)((chunk < 4) ? A3 : A4);
    int kb = (chunk & 3) * 8;
#pragma unroll
    for (int j = 0; j < 4; ++j) {
      int i = t + j * 256;
      int r = i >> 3, kq = i & 7;
      la[j] = make_float4(0.f, 0.f, 0.f, 0.f);
      int gr = row0 + r;
      if (gr < N) la[j] = Av[(size_t)gr * 32 + kb + kq];
    }
#pragma unroll
    for (int j = 0; j < 2; ++j) {
      int i = t + j * 256;
      lw[j] = Wv[(size_t)(chunk * 32 + (i >> 4)) * 16 + (i & 15)];
    }
  };
  auto stage_write = [&](int buf) {
#pragma unroll
    for (int j = 0; j < 4; ++j) {
      int i = t + j * 256;
      int r = i >> 3, kq = i & 7;
      float* p = As[buf] + kq * 4 * 132 + r;
      p[0] = la[j].x; p[132] = la[j].y; p[264] = la[j].z; p[396] = la[j].w;
    }
    float4* Wsv = (float4*)Ws[buf];
#pragma unroll
    for (int j = 0; j < 2; ++j) Wsv[t + j * 256] = lw[j];
  };

  float acc[8][4] = {};
  stage_load(0);
  stage_write(0);
#pragma unroll 1
  for (int c = 0; c < 8; ++c) {
    __syncthreads();
    if (c < 7) stage_load(c + 1);
    const float* At = As[c & 1];
    const float* Wc = Ws[c & 1];
#pragma unroll 4
    for (int k = 0; k < 32; ++k) {
      float4 a0 = *(const float4*)&At[k * 132 + r0];
      float4 a1 = *(const float4*)&At[k * 132 + r0 + 4];
      float4 w = *(const float4*)&Wc[k * 64 + c0];
      float av[8] = {a0.x, a0.y, a0.z, a0.w, a1.x, a1.y, a1.z, a1.w};
      float wv[4] = {w.x, w.y, w.z, w.w};
#pragma unroll
      for (int ii = 0; ii < 8; ++ii)
#pragma unroll
        for (int jj = 0; jj < 4; ++jj)
          acc[ii][jj] += av[ii] * wv[jj];
    }
    if (c < 7) stage_write((c + 1) & 1);
  }

#pragma unroll
  for (int i = 0; i < 8; ++i) {
    int r = row0 + r0 + i;
    if (r < N) {
      ((float4*)Out)[(size_t)r * 16 + (c0 >> 2)] =
          make_float4(acc[i][0], acc[i][1], acc[i][2], acc[i][3]);
    }
  }
}

// ---------------------------------------------------------------------------
extern "C" void kernel_launch(void* const* d_in, const int* in_sizes, int n_in,
                              void* d_out, int out_size, void* d_ws, size_t ws_size,
                              hipStream_t stream) {
  const float* x    = (const float*)d_in[0];
  const int*   src  = (const int*)d_in[1];
  const int*   dst  = (const int*)d_in[2];
  const float* W1   = (const float*)d_in[3];
  const float* b1   = (const float*)d_in[4];
  const float* W2   = (const float*)d_in[5];
  const float* b2   = (const float*)d_in[6];
  const float* Wout = (const float*)d_in[7];
  const float* bout = (const float*)d_in[8];
  float* out = (float*)d_out;

  const int IN = 128;
  const int N = in_sizes[0] / IN;   // 100000
  const int E = in_sizes[1];        // 1600000
  const int ranges = (N + RANGE - 1) / RANGE;  // 4

  char* p = (char*)d_ws;
  auto alloc = [&](size_t bytes) -> char* {
    char* r = p;
    p += (bytes + 255) & ~(size_t)255;
    return r;
  };
  float* buf1   = (float*)alloc((size_t)N * 128 * 4);  // aggA -> h1
  float* buf3   = (float*)alloc((size_t)N * 128 * 4);  // accB -> h2
  float* bufz   = (float*)alloc((size_t)2 * CHUNKS * N * 4); // histD|histS, later z
  float* invo   = (float*)alloc((size_t)N * 4);
  float* invi   = (float*)alloc((size_t)N * 4);
  int* deg_i    = (int*)alloc((size_t)N * 4);
  int* row_ptr  = (int*)alloc((size_t)(N + 1) * 4);
  int* bsums    = (int*)alloc(1024);
  int* boffs    = (int*)alloc(1024);
  int* csr_src  = (int*)alloc((size_t)E * 4);

  // hist arrays alias the (so-far unused) z buffer: dead before k_gemm_z runs.
  int* histD = (int*)bufz;                       // [CHUNKS][N]
  int* histS = histD + (size_t)CHUNKS * N;       // [CHUNKS][N]

  // ---- CSR build: no global atomics ---------------------------------------
  k_hist<<<ranges * CHUNKS * 2, THREADS, 0, stream>>>(dst, src, histD, histS, N, E, ranges);
  k_redinv<<<(N + THREADS - 1) / THREADS, THREADS, 0, stream>>>(histD, histS, deg_i, invi, invo, N);
  int nb1 = (N + 1023) / 1024;
  k_scan1<<<nb1, THREADS, 0, stream>>>(deg_i, row_ptr, bsums, N);
  k_scan2<<<1, 256, 0, stream>>>(bsums, boffs, nb1);
  k_scan3<<<(N + THREADS - 1) / THREADS, THREADS, 0, stream>>>(row_ptr, deg_i, boffs, N, E);
  k_chunkscan<<<(N + THREADS - 1) / THREADS, THREADS, 0, stream>>>(histD, row_ptr, N);
  k_csr<<<ranges * CHUNKS, THREADS, 0, stream>>>(dst, src, histD, csr_src, N, E, ranges);

  const int aggGrid  = (N + (THREADS / 32) - 1) / (THREADS / 32);
  const int aggzGrid = (N + (THREADS / 16) - 1) / (THREADS / 16);
  const int gemmGrid = (N + 127) / 128;

  // ---- layer 1 -------------------------------------------------------------
  k_agg<<<aggGrid, THREADS, 0, stream>>>((const float4*)x, invo, row_ptr, csr_src,
                                         (float4*)buf1, N);
  k_gemm128<true><<<gemmGrid, THREADS, 0, stream>>>(buf1, W1, b1, invi, buf1, N);  // h1

  // ---- layer 2 -------------------------------------------------------------
  k_agg<<<aggGrid, THREADS, 0, stream>>>((const float4*)buf1, invo, row_ptr, csr_src,
                                         (float4*)buf3, N);
  k_gemm128<true><<<gemmGrid, THREADS, 0, stream>>>(buf3, W2, b2, invi, buf3, N);  // h2

  // ---- z = h1@Wo1 + h2@Wo2 then out = A@z + bout ---------------------------
  k_gemm_z<<<gemmGrid, THREADS, 0, stream>>>(buf1, buf3, Wout, bufz, N);
  k_agg_z<<<aggzGrid, THREADS, 0, stream>>>((const float4*)bufz, row_ptr, csr_src,
                                            bout, (float4*)out, N);
}

// Round 8
// 587.639 us; speedup vs baseline: 1.1526x; 1.1526x over previous
//
#include <hip/hip_runtime.h>
#include <cstddef>
#include <cstdint>

// ---------------------------------------------------------------------------
// JKNet: h1 = relu((D_in^-1/2 A D_out^-1/2 x) @ W1 + b1)
//        h2 = relu((D_in^-1/2 A D_out^-1/2 h1) @ W2 + b2)
//        out = A@(h1@Wo1 + h2@Wo2) + bout   (bout folded into final gather)
// Aggregate-first refactor (SpMM commutes with dense GEMM).
// R3: atomic-free CSR build (LDS histograms; global atomics are memory-side
//     on gfx950, ~40ns each).
// R6 null result: NT stores + 4-edge unroll left k_agg at 120us/390MB FETCH.
//     FETCH == 8 XCDs x 51.2MB table == architectural minimum for private
//     L2s -> gather is beyond-L2-traffic-bound. Only lever: shrink the table.
// R7: fp16 gather operands (rel err 5e-4), invout row-scale folded into the
//     operand at production time (cast pass for x; GEMM epilogue for h1).
//     Gather = pure unweighted fp16 row sum, f32 accumulation. z-gather
//     stays f32 (its error would hit the output directly).
// ---------------------------------------------------------------------------

#define THREADS 256
#define RANGE 25600      // nodes per LDS histogram slice (100 KB LDS)
#define CHUNKS 32        // edge chunks

typedef float f32x4 __attribute__((ext_vector_type(4)));
typedef __fp16 half8 __attribute__((ext_vector_type(8)));

__device__ __forceinline__ void nt_store_f4(const float4 s, float4* dst) {
  f32x4 v; v.x = s.x; v.y = s.y; v.z = s.z; v.w = s.w;
  __builtin_nontemporal_store(v, (f32x4*)dst);
}

__device__ __forceinline__ float4 f4_add(const float4 v, float4 a) {
  a.x += v.x; a.y += v.y; a.z += v.z; a.w += v.w; return a;
}

// ---- 2D histogram: hist[c][v] = #edges in chunk c with key==v ---------------
__global__ __launch_bounds__(THREADS)
void k_hist(const int* __restrict__ dst, const int* __restrict__ src,
            int* __restrict__ histD, int* __restrict__ histS,
            int N, int E, int ranges) {
  __shared__ int h[RANGE];
  int aid = blockIdx.x & 1;
  int r = (blockIdx.x >> 1) % ranges;
  int c = (blockIdx.x >> 1) / ranges;
  const int* arr = aid ? src : dst;
  int* hist = aid ? histS : histD;
  int lo = r * RANGE;
  unsigned span = (unsigned)min(RANGE, N - lo);
  int t = threadIdx.x;
  for (int j = t; j < RANGE; j += THREADS) h[j] = 0;
  __syncthreads();

  int beg = (int)((long long)c * E / CHUNKS);
  int end = (int)((long long)(c + 1) * E / CHUNKS);
  int a = min(end, (beg + 3) & ~3);
  for (int i = beg + t; i < a; i += THREADS) {
    unsigned u = (unsigned)(arr[i] - lo);
    if (u < span) atomicAdd(&h[u], 1);
  }
  for (int i4 = a + t * 4; i4 + 3 < end; i4 += THREADS * 4) {
    int4 v = *(const int4*)(arr + i4);
    unsigned u0 = (unsigned)(v.x - lo), u1 = (unsigned)(v.y - lo);
    unsigned u2 = (unsigned)(v.z - lo), u3 = (unsigned)(v.w - lo);
    if (u0 < span) atomicAdd(&h[u0], 1);
    if (u1 < span) atomicAdd(&h[u1], 1);
    if (u2 < span) atomicAdd(&h[u2], 1);
    if (u3 < span) atomicAdd(&h[u3], 1);
  }
  int tail = a + ((end - a) & ~3);
  for (int i = tail + t; i < end; i += THREADS) {
    unsigned u = (unsigned)(arr[i] - lo);
    if (u < span) atomicAdd(&h[u], 1);
  }
  __syncthreads();
  for (int j = t; j < (int)span; j += THREADS) hist[(size_t)c * N + lo + j] = h[j];
}

// ---- reduce hist columns -> deg_i, invi, invo ------------------------------
__global__ void k_redinv(const int* __restrict__ histD, const int* __restrict__ histS,
                         int* __restrict__ deg_i, float* __restrict__ inv_in,
                         float* __restrict__ inv_out, int N) {
  int v = blockIdx.x * blockDim.x + threadIdx.x;
  if (v >= N) return;
  int sD = 0, sS = 0;
#pragma unroll
  for (int c = 0; c < CHUNKS; ++c) {
    sD += histD[(size_t)c * N + v];
    sS += histS[(size_t)c * N + v];
  }
  deg_i[v] = sD;
  inv_in[v]  = rsqrtf((float)max(sD, 1));
  inv_out[v] = rsqrtf((float)max(sS, 1));
}

// ---- exclusive scan of deg_i -> row_ptr (3 kernels, chunk=1024) ------------
__global__ void k_scan1(const int* __restrict__ deg, int* __restrict__ incl,
                        int* __restrict__ bsums, int N) {
  __shared__ int sd[1024];
  int base = blockIdx.x * 1024;
  for (int j = threadIdx.x; j < 1024; j += THREADS) sd[j] = (base + j < N) ? deg[base + j] : 0;
  __syncthreads();
  for (int off = 1; off < 1024; off <<= 1) {
    int v[4];
#pragma unroll
    for (int k = 0; k < 4; ++k) { int j = threadIdx.x + k * THREADS; v[k] = (j >= off) ? sd[j - off] : 0; }
    __syncthreads();
#pragma unroll
    for (int k = 0; k < 4; ++k) { int j = threadIdx.x + k * THREADS; sd[j] += v[k]; }
    __syncthreads();
  }
  for (int j = threadIdx.x; j < 1024; j += THREADS) if (base + j < N) incl[base + j] = sd[j];
  if (threadIdx.x == 0) bsums[blockIdx.x] = sd[1023];
}

__global__ void k_scan2(const int* __restrict__ bsums, int* __restrict__ boffs, int nb) {
  __shared__ int sd[256];
  int t = threadIdx.x;
  sd[t] = (t < nb) ? bsums[t] : 0;
  __syncthreads();
  for (int off = 1; off < 256; off <<= 1) {
    int v = (t >= off) ? sd[t - off] : 0;
    __syncthreads();
    sd[t] += v;
    __syncthreads();
  }
  if (t < nb) boffs[t] = (t == 0) ? 0 : sd[t - 1];
}

__global__ void k_scan3(int* __restrict__ incl_rowptr, const int* __restrict__ deg,
                        const int* __restrict__ boffs, int N, int E) {
  int i = blockIdx.x * blockDim.x + threadIdx.x;
  if (i < N) incl_rowptr[i] = incl_rowptr[i] - deg[i] + boffs[i >> 10];
  if (i == 0) incl_rowptr[N] = E;
}

// ---- chunk-scan: histD[c][v] -> scatter offset base row_ptr[v]+prefix ------
__global__ void k_chunkscan(int* __restrict__ histD, const int* __restrict__ row_ptr, int N) {
  int v = blockIdx.x * blockDim.x + threadIdx.x;
  if (v >= N) return;
  int run = row_ptr[v];
#pragma unroll
  for (int c = 0; c < CHUNKS; ++c) {
    size_t idx = (size_t)c * N + v;
    int t = histD[idx];
    histD[idx] = run;
    run += t;
  }
}

// ---- CSR fill: rank via LDS atomic on range slice of offsets ---------------
__global__ __launch_bounds__(THREADS)
void k_csr(const int* __restrict__ dst, const int* __restrict__ src,
           const int* __restrict__ offs, int* __restrict__ csr_src,
           int N, int E, int ranges) {
  __shared__ int offL[RANGE];
  int r = blockIdx.x % ranges;
  int c = blockIdx.x / ranges;
  int lo = r * RANGE;
  unsigned span = (unsigned)min(RANGE, N - lo);
  int t = threadIdx.x;
  for (int j = t; j < (int)span; j += THREADS) offL[j] = offs[(size_t)c * N + lo + j];
  __syncthreads();

  int beg = (int)((long long)c * E / CHUNKS);
  int end = (int)((long long)(c + 1) * E / CHUNKS);
  int a = min(end, (beg + 3) & ~3);
  for (int i = beg + t; i < a; i += THREADS) {
    unsigned u = (unsigned)(dst[i] - lo);
    if (u < span) csr_src[atomicAdd(&offL[u], 1)] = src[i];
  }
  for (int i4 = a + t * 4; i4 + 3 < end; i4 += THREADS * 4) {
    int4 d = *(const int4*)(dst + i4);
    int4 s = *(const int4*)(src + i4);
    unsigned u0 = (unsigned)(d.x - lo), u1 = (unsigned)(d.y - lo);
    unsigned u2 = (unsigned)(d.z - lo), u3 = (unsigned)(d.w - lo);
    if (u0 < span) csr_src[atomicAdd(&offL[u0], 1)] = s.x;
    if (u1 < span) csr_src[atomicAdd(&offL[u1], 1)] = s.y;
    if (u2 < span) csr_src[atomicAdd(&offL[u2], 1)] = s.z;
    if (u3 < span) csr_src[atomicAdd(&offL[u3], 1)] = s.w;
  }
  int tail = a + ((end - a) & ~3);
  for (int i = tail + t; i < end; i += THREADS) {
    unsigned u = (unsigned)(dst[i] - lo);
    if (u < span) csr_src[atomicAdd(&offL[u], 1)] = src[i];
  }
}

// ---- cast+scale: XS[v] = fp16(x[v] * invout[v]) ----------------------------
__global__ __launch_bounds__(THREADS)
void k_cast_scale(const float4* __restrict__ X, const float* __restrict__ invo,
                  half8* __restrict__ XS, int N) {
  int i = blockIdx.x * blockDim.x + threadIdx.x;   // one half8 (8 floats) each
  if (i >= N * 16) return;
  int row = i >> 4;
  float s = invo[row];
  float4 a = X[(size_t)i * 2];
  float4 b = X[(size_t)i * 2 + 1];
  half8 h;
  h[0] = (__fp16)(a.x * s); h[1] = (__fp16)(a.y * s);
  h[2] = (__fp16)(a.z * s); h[3] = (__fp16)(a.w * s);
  h[4] = (__fp16)(b.x * s); h[5] = (__fp16)(b.y * s);
  h[6] = (__fp16)(b.z * s); h[7] = (__fp16)(b.w * s);
  XS[i] = h;
}

// ---- fp16 CSR aggregation (128-wide): O1[v] = sum_{e:dst=v} H[src] ---------
// invout pre-folded into H. 16 lanes/node x 16B; f32 accumulation.
__global__ __launch_bounds__(THREADS)
void k_agg_h(const half8* __restrict__ H, const int* __restrict__ row_ptr,
             const int* __restrict__ csr_src, float4* __restrict__ O1, int N) {
  int g = blockIdx.x * (THREADS / 16) + (threadIdx.x >> 4);
  int lane = threadIdx.x & 15;
  if (g >= N) return;
  int e = row_ptr[g], end = row_ptr[g + 1];
  float sa[8] = {0.f, 0.f, 0.f, 0.f, 0.f, 0.f, 0.f, 0.f};
  float sb[8] = {0.f, 0.f, 0.f, 0.f, 0.f, 0.f, 0.f, 0.f};
  for (; e + 1 < end; e += 2) {
    int n0 = csr_src[e], n1 = csr_src[e + 1];
    half8 v0 = H[(size_t)n0 * 16 + lane];
    half8 v1 = H[(size_t)n1 * 16 + lane];
#pragma unroll
    for (int j = 0; j < 8; ++j) { sa[j] += (float)v0[j]; sb[j] += (float)v1[j]; }
  }
  if (e < end) {
    half8 v0 = H[(size_t)csr_src[e] * 16 + lane];
#pragma unroll
    for (int j = 0; j < 8; ++j) sa[j] += (float)v0[j];
  }
  float4 o0 = make_float4(sa[0] + sb[0], sa[1] + sb[1], sa[2] + sb[2], sa[3] + sb[3]);
  float4 o1 = make_float4(sa[4] + sb[4], sa[5] + sb[5], sa[6] + sb[6], sa[7] + sb[7]);
  nt_store_f4(o0, &O1[(size_t)g * 32 + lane * 2]);
  nt_store_f4(o1, &O1[(size_t)g * 32 + lane * 2 + 1]);
}

// ---- CSR aggregation (64-wide f32, +bout): out = sum z[src] + bout ---------
__global__ __launch_bounds__(THREADS)
void k_agg_z(const float4* __restrict__ Z, const int* __restrict__ row_ptr,
             const int* __restrict__ csr_src, const float* __restrict__ bo,
             float4* __restrict__ Out, int N) {
  int g = blockIdx.x * (THREADS / 16) + (threadIdx.x >> 4);
  int lane = threadIdx.x & 15;
  if (g >= N) return;
  int e = row_ptr[g], end = row_ptr[g + 1];
  float4 sa = ((const float4*)bo)[lane];
  float4 sb = make_float4(0.f, 0.f, 0.f, 0.f);
  for (; e + 3 < end; e += 4) {
    int n0 = csr_src[e], n1 = csr_src[e + 1], n2 = csr_src[e + 2], n3 = csr_src[e + 3];
    float4 v0 = Z[(size_t)n0 * 16 + lane];
    float4 v1 = Z[(size_t)n1 * 16 + lane];
    float4 v2 = Z[(size_t)n2 * 16 + lane];
    float4 v3 = Z[(size_t)n3 * 16 + lane];
    sa = f4_add(v0, sa); sb = f4_add(v1, sb);
    sa = f4_add(v2, sa); sb = f4_add(v3, sb);
  }
  for (; e < end; ++e) sa = f4_add(Z[(size_t)csr_src[e] * 16 + lane], sa);
  float4 s = f4_add(sa, sb);
  nt_store_f4(s, &Out[(size_t)g * 16 + lane]);
}

// ---- 128x128 GEMM, fused scale+bias+relu (+optional fp16 scaled output) ----
// Out[r][c] = relu((sum_k A[r][k]*W[k][c]) * scale[r] + bias[c])
// H16OUT: additionally H16[r][c] = fp16(Out[r][c] * invo[r])  (gather operand)
template <bool RELU, bool H16OUT>
__global__ __launch_bounds__(THREADS, 2)
void k_gemm128(const float* __restrict__ A, const float* __restrict__ W,
               const float* __restrict__ bias, const float* __restrict__ scale,
               float* __restrict__ Out, const float* __restrict__ invo,
               half8* __restrict__ H16, int N) {
  __shared__ float As[2][32 * 132];   // transposed: As[k][row], stride 132
  __shared__ float Ws[2][32 * 128];   // Ws[k][col]
  int t = threadIdx.x;
  int row0 = blockIdx.x * 128;
  int tx = t & 15, ty = t >> 4;
  int c0 = tx * 8, r0 = ty * 8;

  const float4* Av = (const float4*)A;
  const float4* Wv = (const float4*)W;

  float4 la[4], lw[4];
  auto stage_load = [&](int chunk) {
#pragma unroll
    for (int j = 0; j < 4; ++j) {
      int i = t + j * 256;
      int r = i >> 3, kq = i & 7;
      la[j] = make_float4(0.f, 0.f, 0.f, 0.f);
      int gr = row0 + r;
      if (gr < N) la[j] = Av[(size_t)gr * 32 + chunk * 8 + kq];
    }
#pragma unroll
    for (int j = 0; j < 4; ++j) {
      int i = t + j * 256;
      lw[j] = Wv[(size_t)(chunk * 32 + (i >> 5)) * 32 + (i & 31)];
    }
  };
  auto stage_write = [&](int buf) {
#pragma unroll
    for (int j = 0; j < 4; ++j) {
      int i = t + j * 256;
      int r = i >> 3, kq = i & 7;
      float* p = As[buf] + kq * 4 * 132 + r;
      p[0] = la[j].x; p[132] = la[j].y; p[264] = la[j].z; p[396] = la[j].w;
    }
    float4* Wsv = (float4*)Ws[buf];
#pragma unroll
    for (int j = 0; j < 4; ++j) Wsv[t + j * 256] = lw[j];
  };

  float acc[8][8] = {};
  stage_load(0);
  stage_write(0);
#pragma unroll 1
  for (int c = 0; c < 4; ++c) {
    __syncthreads();
    if (c < 3) stage_load(c + 1);
    const float* At = As[c & 1];
    const float* Wc = Ws[c & 1];
#pragma unroll 4
    for (int k = 0; k < 32; ++k) {
      float4 a0 = *(const float4*)&At[k * 132 + r0];
      float4 a1 = *(const float4*)&At[k * 132 + r0 + 4];
      float4 w0 = *(const float4*)&Wc[k * 128 + c0];
      float4 w1 = *(const float4*)&Wc[k * 128 + c0 + 4];
      float av[8] = {a0.x, a0.y, a0.z, a0.w, a1.x, a1.y, a1.z, a1.w};
      float wv[8] = {w0.x, w0.y, w0.z, w0.w, w1.x, w1.y, w1.z, w1.w};
#pragma unroll
      for (int ii = 0; ii < 8; ++ii)
#pragma unroll
        for (int jj = 0; jj < 8; ++jj)
          acc[ii][jj] += av[ii] * wv[jj];
    }
    if (c < 3) stage_write((c + 1) & 1);
  }

  float bj[8];
#pragma unroll
  for (int j = 0; j < 8; ++j) bj[j] = bias[c0 + j];
#pragma unroll
  for (int i = 0; i < 8; ++i) {
    int r = row0 + r0 + i;
    if (r < N) {
      float s = scale[r];
      float o[8];
#pragma unroll
      for (int j = 0; j < 8; ++j) {
        float v = acc[i][j] * s + bj[j];
        o[j] = RELU ? fmaxf(v, 0.f) : v;
      }
      float4* op = (float4*)Out + (size_t)r * 32 + (c0 >> 2);
      op[0] = make_float4(o[0], o[1], o[2], o[3]);
      op[1] = make_float4(o[4], o[5], o[6], o[7]);
      if (H16OUT) {
        float so = invo[r];
        half8 hh;
#pragma unroll
        for (int j = 0; j < 8; ++j) hh[j] = (__fp16)(o[j] * so);
        H16[(size_t)r * 16 + tx] = hh;
      }
    }
  }
}

// ---- z GEMM: Z = A3 @ Wo[0:128] + A4 @ Wo[128:256]  (N x 64) ---------------
__global__ __launch_bounds__(THREADS, 3)
void k_gemm_z(const float* __restrict__ A3, const float* __restrict__ A4,
              const float* __restrict__ Wo, float* __restrict__ Out, int N) {
  __shared__ float As[2][32 * 132];
  __shared__ float Ws[2][32 * 64];
  int t = threadIdx.x;
  int row0 = blockIdx.x * 128;
  int tx = t & 15, ty = t >> 4;
  int c0 = tx * 4, r0 = ty * 8;

  const float4* Wv = (const float4*)Wo;

  float4 la[4], lw[2];
  auto stage_load = [&](int chunk) {
    const float4* Av = (const float4*)((chunk < 4) ? A3 : A4);
    int kb = (chunk & 3) * 8;
#pragma unroll
    for (int j = 0; j < 4; ++j) {
      int i = t + j * 256;
      int r = i >> 3, kq = i & 7;
      la[j] = make_float4(0.f, 0.f, 0.f, 0.f);
      int gr = row0 + r;
      if (gr < N) la[j] = Av[(size_t)gr * 32 + kb + kq];
    }
#pragma unroll
    for (int j = 0; j < 2; ++j) {
      int i = t + j * 256;
      lw[j] = Wv[(size_t)(chunk * 32 + (i >> 4)) * 16 + (i & 15)];
    }
  };
  auto stage_write = [&](int buf) {
#pragma unroll
    for (int j = 0; j < 4; ++j) {
      int i = t + j * 256;
      int r = i >> 3, kq = i & 7;
      float* p = As[buf] + kq * 4 * 132 + r;
      p[0] = la[j].x; p[132] = la[j].y; p[264] = la[j].z; p[396] = la[j].w;
    }
    float4* Wsv = (float4*)Ws[buf];
#pragma unroll
    for (int j = 0; j < 2; ++j) Wsv[t + j * 256] = lw[j];
  };

  float acc[8][4] = {};
  stage_load(0);
  stage_write(0);
#pragma unroll 1
  for (int c = 0; c < 8; ++c) {
    __syncthreads();
    if (c < 7) stage_load(c + 1);
    const float* At = As[c & 1];
    const float* Wc = Ws[c & 1];
#pragma unroll 4
    for (int k = 0; k < 32; ++k) {
      float4 a0 = *(const float4*)&At[k * 132 + r0];
      float4 a1 = *(const float4*)&At[k * 132 + r0 + 4];
      float4 w = *(const float4*)&Wc[k * 64 + c0];
      float av[8] = {a0.x, a0.y, a0.z, a0.w, a1.x, a1.y, a1.z, a1.w};
      float wv[4] = {w.x, w.y, w.z, w.w};
#pragma unroll
      for (int ii = 0; ii < 8; ++ii)
#pragma unroll
        for (int jj = 0; jj < 4; ++jj)
          acc[ii][jj] += av[ii] * wv[jj];
    }
    if (c < 7) stage_write((c + 1) & 1);
  }

#pragma unroll
  for (int i = 0; i < 8; ++i) {
    int r = row0 + r0 + i;
    if (r < N) {
      ((float4*)Out)[(size_t)r * 16 + (c0 >> 2)] =
          make_float4(acc[i][0], acc[i][1], acc[i][2], acc[i][3]);
    }
  }
}

// ---------------------------------------------------------------------------
extern "C" void kernel_launch(void* const* d_in, const int* in_sizes, int n_in,
                              void* d_out, int out_size, void* d_ws, size_t ws_size,
                              hipStream_t stream) {
  const float* x    = (const float*)d_in[0];
  const int*   src  = (const int*)d_in[1];
  const int*   dst  = (const int*)d_in[2];
  const float* W1   = (const float*)d_in[3];
  const float* b1   = (const float*)d_in[4];
  const float* W2   = (const float*)d_in[5];
  const float* b2   = (const float*)d_in[6];
  const float* Wout = (const float*)d_in[7];
  const float* bout = (const float*)d_in[8];
  float* out = (float*)d_out;

  const int IN = 128;
  const int N = in_sizes[0] / IN;   // 100000
  const int E = in_sizes[1];        // 1600000
  const int ranges = (N + RANGE - 1) / RANGE;  // 4

  char* p = (char*)d_ws;
  auto alloc = [&](size_t bytes) -> char* {
    char* r = p;
    p += (bytes + 255) & ~(size_t)255;
    return r;
  };
  float* buf1   = (float*)alloc((size_t)N * 128 * 4);  // aggA -> h1
  float* buf3   = (float*)alloc((size_t)N * 128 * 4);  // accB -> h2
  float* bufz   = (float*)alloc((size_t)2 * CHUNKS * N * 4); // histD|histS, later z
  half8* bufh16 = (half8*)alloc((size_t)N * 128 * 2);  // xs, then h1s (fp16)
  float* invo   = (float*)alloc((size_t)N * 4);
  float* invi   = (float*)alloc((size_t)N * 4);
  int* deg_i    = (int*)alloc((size_t)N * 4);
  int* row_ptr  = (int*)alloc((size_t)(N + 1) * 4);
  int* bsums    = (int*)alloc(1024);
  int* boffs    = (int*)alloc(1024);
  int* csr_src  = (int*)alloc((size_t)E * 4);

  // hist arrays alias the (so-far unused) z buffer: dead before k_gemm_z runs.
  int* histD = (int*)bufz;                       // [CHUNKS][N]
  int* histS = histD + (size_t)CHUNKS * N;       // [CHUNKS][N]

  // ---- CSR build: no global atomics ---------------------------------------
  k_hist<<<ranges * CHUNKS * 2, THREADS, 0, stream>>>(dst, src, histD, histS, N, E, ranges);
  k_redinv<<<(N + THREADS - 1) / THREADS, THREADS, 0, stream>>>(histD, histS, deg_i, invi, invo, N);
  int nb1 = (N + 1023) / 1024;
  k_scan1<<<nb1, THREADS, 0, stream>>>(deg_i, row_ptr, bsums, N);
  k_scan2<<<1, 256, 0, stream>>>(bsums, boffs, nb1);
  k_scan3<<<(N + THREADS - 1) / THREADS, THREADS, 0, stream>>>(row_ptr, deg_i, boffs, N, E);
  k_chunkscan<<<(N + THREADS - 1) / THREADS, THREADS, 0, stream>>>(histD, row_ptr, N);
  k_csr<<<ranges * CHUNKS, THREADS, 0, stream>>>(dst, src, histD, csr_src, N, E, ranges);

  const int aggGrid  = (N + (THREADS / 16) - 1) / (THREADS / 16);
  const int gemmGrid = (N + 127) / 128;
  const int castGrid = (N * 16 + THREADS - 1) / THREADS;

  // ---- layer 1: xs = fp16(x*invo); aggA = A@xs; h1 = relu(aggA@W1*invi+b1) -
  k_cast_scale<<<castGrid, THREADS, 0, stream>>>((const float4*)x, invo, bufh16, N);
  k_agg_h<<<aggGrid, THREADS, 0, stream>>>(bufh16, row_ptr, csr_src, (float4*)buf1, N);
  k_gemm128<true, true><<<gemmGrid, THREADS, 0, stream>>>(buf1, W1, b1, invi, buf1,
                                                          invo, bufh16, N);  // h1 + h1s

  // ---- layer 2: aggB = A@h1s; h2 = relu(aggB@W2*invi+b2) -------------------
  k_agg_h<<<aggGrid, THREADS, 0, stream>>>(bufh16, row_ptr, csr_src, (float4*)buf3, N);
  k_gemm128<true, false><<<gemmGrid, THREADS, 0, stream>>>(buf3, W2, b2, invi, buf3,
                                                           nullptr, nullptr, N);  // h2

  // ---- z = h1@Wo1 + h2@Wo2 then out = A@z + bout ---------------------------
  k_gemm_z<<<gemmGrid, THREADS, 0, stream>>>(buf1, buf3, Wout, bufz, N);
  k_agg_z<<<aggGrid, THREADS, 0, stream>>>((const float4*)bufz, row_ptr, csr_src,
                                           bout, (float4*)out, N);
}

// Round 9
// 479.938 us; speedup vs baseline: 1.4113x; 1.2244x over previous
//
#include <hip/hip_runtime.h>
#include <cstddef>
#include <cstdint>

// ---------------------------------------------------------------------------
// JKNet, aggregate-first + fp16 hidden states + MFMA GEMMs.
//   xs = fp16(x*invo);           aggA = A@xs (fp16 out)
//   h1 = relu((aggA@W1)*invi+b1) via MFMA; emits h1s=fp16(h1*invo), h1h=fp16(h1)
//   aggB = A@h1s (fp16 out);     h2h = fp16(relu((aggB@W2)*invi+b2)) via MFMA
//   z = h1h@Wo1 + h2h@Wo2 (f32) via MFMA (K=256 in two 128-halves)
//   out[v] = sum_{e:dst=v} z[src] + bout   (f32 gather)
// R8: all GEMMs on v_mfma_f32_16x16x32_f16 (A row=lane&15,k=(lane>>4)*8+j;
//     B col=lane&15; D col=lane&15,row=(lane>>4)*4+reg — m89/m91-verified
//     mapping). LDS rows padded to 136 halfs (272B = 17x16B -> 2-way bank
//     aliasing = free). No f32 hidden-state buffers at all.
// ---------------------------------------------------------------------------

#define THREADS 256
#define RANGE 25600      // nodes per LDS histogram slice (100 KB LDS)
#define CHUNKS 32        // edge chunks

typedef float f32x4 __attribute__((ext_vector_type(4)));
typedef _Float16 h8 __attribute__((ext_vector_type(8)));

__device__ __forceinline__ void nt_store_f4(const float4 s, float4* dst) {
  f32x4 v; v.x = s.x; v.y = s.y; v.z = s.z; v.w = s.w;
  __builtin_nontemporal_store(v, (f32x4*)dst);
}
__device__ __forceinline__ float4 f4_add(const float4 v, float4 a) {
  a.x += v.x; a.y += v.y; a.z += v.z; a.w += v.w; return a;
}

// ---- 2D histogram: hist[c][v] = #edges in chunk c with key==v ---------------
__global__ __launch_bounds__(THREADS)
void k_hist(const int* __restrict__ dst, const int* __restrict__ src,
            int* __restrict__ histD, int* __restrict__ histS,
            int N, int E, int ranges) {
  __shared__ int h[RANGE];
  int aid = blockIdx.x & 1;
  int r = (blockIdx.x >> 1) % ranges;
  int c = (blockIdx.x >> 1) / ranges;
  const int* arr = aid ? src : dst;
  int* hist = aid ? histS : histD;
  int lo = r * RANGE;
  unsigned span = (unsigned)min(RANGE, N - lo);
  int t = threadIdx.x;
  for (int j = t; j < RANGE; j += THREADS) h[j] = 0;
  __syncthreads();

  int beg = (int)((long long)c * E / CHUNKS);
  int end = (int)((long long)(c + 1) * E / CHUNKS);
  int a = min(end, (beg + 3) & ~3);
  for (int i = beg + t; i < a; i += THREADS) {
    unsigned u = (unsigned)(arr[i] - lo);
    if (u < span) atomicAdd(&h[u], 1);
  }
  for (int i4 = a + t * 4; i4 + 3 < end; i4 += THREADS * 4) {
    int4 v = *(const int4*)(arr + i4);
    unsigned u0 = (unsigned)(v.x - lo), u1 = (unsigned)(v.y - lo);
    unsigned u2 = (unsigned)(v.z - lo), u3 = (unsigned)(v.w - lo);
    if (u0 < span) atomicAdd(&h[u0], 1);
    if (u1 < span) atomicAdd(&h[u1], 1);
    if (u2 < span) atomicAdd(&h[u2], 1);
    if (u3 < span) atomicAdd(&h[u3], 1);
  }
  int tail = a + ((end - a) & ~3);
  for (int i = tail + t; i < end; i += THREADS) {
    unsigned u = (unsigned)(arr[i] - lo);
    if (u < span) atomicAdd(&h[u], 1);
  }
  __syncthreads();
  for (int j = t; j < (int)span; j += THREADS) hist[(size_t)c * N + lo + j] = h[j];
}

// ---- reduce hist columns -> deg_i, invi, invo ------------------------------
__global__ void k_redinv(const int* __restrict__ histD, const int* __restrict__ histS,
                         int* __restrict__ deg_i, float* __restrict__ inv_in,
                         float* __restrict__ inv_out, int N) {
  int v = blockIdx.x * blockDim.x + threadIdx.x;
  if (v >= N) return;
  int sD = 0, sS = 0;
#pragma unroll
  for (int c = 0; c < CHUNKS; ++c) {
    sD += histD[(size_t)c * N + v];
    sS += histS[(size_t)c * N + v];
  }
  deg_i[v] = sD;
  inv_in[v]  = rsqrtf((float)max(sD, 1));
  inv_out[v] = rsqrtf((float)max(sS, 1));
}

// ---- exclusive scan of deg_i -> row_ptr (3 kernels, chunk=1024) ------------
__global__ void k_scan1(const int* __restrict__ deg, int* __restrict__ incl,
                        int* __restrict__ bsums, int N) {
  __shared__ int sd[1024];
  int base = blockIdx.x * 1024;
  for (int j = threadIdx.x; j < 1024; j += THREADS) sd[j] = (base + j < N) ? deg[base + j] : 0;
  __syncthreads();
  for (int off = 1; off < 1024; off <<= 1) {
    int v[4];
#pragma unroll
    for (int k = 0; k < 4; ++k) { int j = threadIdx.x + k * THREADS; v[k] = (j >= off) ? sd[j - off] : 0; }
    __syncthreads();
#pragma unroll
    for (int k = 0; k < 4; ++k) { int j = threadIdx.x + k * THREADS; sd[j] += v[k]; }
    __syncthreads();
  }
  for (int j = threadIdx.x; j < 1024; j += THREADS) if (base + j < N) incl[base + j] = sd[j];
  if (threadIdx.x == 0) bsums[blockIdx.x] = sd[1023];
}

__global__ void k_scan2(const int* __restrict__ bsums, int* __restrict__ boffs, int nb) {
  __shared__ int sd[256];
  int t = threadIdx.x;
  sd[t] = (t < nb) ? bsums[t] : 0;
  __syncthreads();
  for (int off = 1; off < 256; off <<= 1) {
    int v = (t >= off) ? sd[t - off] : 0;
    __syncthreads();
    sd[t] += v;
    __syncthreads();
  }
  if (t < nb) boffs[t] = (t == 0) ? 0 : sd[t - 1];
}

__global__ void k_scan3(int* __restrict__ incl_rowptr, const int* __restrict__ deg,
                        const int* __restrict__ boffs, int N, int E) {
  int i = blockIdx.x * blockDim.x + threadIdx.x;
  if (i < N) incl_rowptr[i] = incl_rowptr[i] - deg[i] + boffs[i >> 10];
  if (i == 0) incl_rowptr[N] = E;
}

// ---- chunk-scan: histD[c][v] -> scatter offset base row_ptr[v]+prefix ------
__global__ void k_chunkscan(int* __restrict__ histD, const int* __restrict__ row_ptr, int N) {
  int v = blockIdx.x * blockDim.x + threadIdx.x;
  if (v >= N) return;
  int run = row_ptr[v];
#pragma unroll
  for (int c = 0; c < CHUNKS; ++c) {
    size_t idx = (size_t)c * N + v;
    int t = histD[idx];
    histD[idx] = run;
    run += t;
  }
}

// ---- CSR fill: rank via LDS atomic on range slice of offsets ---------------
__global__ __launch_bounds__(THREADS)
void k_csr(const int* __restrict__ dst, const int* __restrict__ src,
           const int* __restrict__ offs, int* __restrict__ csr_src,
           int N, int E, int ranges) {
  __shared__ int offL[RANGE];
  int r = blockIdx.x % ranges;
  int c = blockIdx.x / ranges;
  int lo = r * RANGE;
  unsigned span = (unsigned)min(RANGE, N - lo);
  int t = threadIdx.x;
  for (int j = t; j < (int)span; j += THREADS) offL[j] = offs[(size_t)c * N + lo + j];
  __syncthreads();

  int beg = (int)((long long)c * E / CHUNKS);
  int end = (int)((long long)(c + 1) * E / CHUNKS);
  int a = min(end, (beg + 3) & ~3);
  for (int i = beg + t; i < a; i += THREADS) {
    unsigned u = (unsigned)(dst[i] - lo);
    if (u < span) csr_src[atomicAdd(&offL[u], 1)] = src[i];
  }
  for (int i4 = a + t * 4; i4 + 3 < end; i4 += THREADS * 4) {
    int4 d = *(const int4*)(dst + i4);
    int4 s = *(const int4*)(src + i4);
    unsigned u0 = (unsigned)(d.x - lo), u1 = (unsigned)(d.y - lo);
    unsigned u2 = (unsigned)(d.z - lo), u3 = (unsigned)(d.w - lo);
    if (u0 < span) csr_src[atomicAdd(&offL[u0], 1)] = s.x;
    if (u1 < span) csr_src[atomicAdd(&offL[u1], 1)] = s.y;
    if (u2 < span) csr_src[atomicAdd(&offL[u2], 1)] = s.z;
    if (u3 < span) csr_src[atomicAdd(&offL[u3], 1)] = s.w;
  }
  int tail = a + ((end - a) & ~3);
  for (int i = tail + t; i < end; i += THREADS) {
    unsigned u = (unsigned)(dst[i] - lo);
    if (u < span) csr_src[atomicAdd(&offL[u], 1)] = src[i];
  }
}

// ---- cast+scale: XS[v] = fp16(x[v] * invout[v]) ----------------------------
__global__ __launch_bounds__(THREADS)
void k_cast_scale(const float4* __restrict__ X, const float* __restrict__ invo,
                  h8* __restrict__ XS, int N) {
  int i = blockIdx.x * blockDim.x + threadIdx.x;   // one h8 (8 floats) each
  if (i >= N * 16) return;
  int row = i >> 4;
  float s = invo[row];
  float4 a = X[(size_t)i * 2];
  float4 b = X[(size_t)i * 2 + 1];
  h8 h;
  h[0] = (_Float16)(a.x * s); h[1] = (_Float16)(a.y * s);
  h[2] = (_Float16)(a.z * s); h[3] = (_Float16)(a.w * s);
  h[4] = (_Float16)(b.x * s); h[5] = (_Float16)(b.y * s);
  h[6] = (_Float16)(b.z * s); h[7] = (_Float16)(b.w * s);
  XS[i] = h;
}

// ---- fp16 CSR aggregation: O[v] = fp16( sum_{e:dst=v} H[src] ) -------------
// invout pre-folded into H. 16 lanes/node x 16B; f32 accumulation, fp16 out.
__global__ __launch_bounds__(THREADS)
void k_agg_h(const h8* __restrict__ H, const int* __restrict__ row_ptr,
             const int* __restrict__ csr_src, h8* __restrict__ O, int N) {
  int g = blockIdx.x * (THREADS / 16) + (threadIdx.x >> 4);
  int lane = threadIdx.x & 15;
  if (g >= N) return;
  int e = row_ptr[g], end = row_ptr[g + 1];
  float sa[8] = {0.f, 0.f, 0.f, 0.f, 0.f, 0.f, 0.f, 0.f};
  float sb[8] = {0.f, 0.f, 0.f, 0.f, 0.f, 0.f, 0.f, 0.f};
  for (; e + 1 < end; e += 2) {
    int n0 = csr_src[e], n1 = csr_src[e + 1];
    h8 v0 = H[(size_t)n0 * 16 + lane];
    h8 v1 = H[(size_t)n1 * 16 + lane];
#pragma unroll
    for (int j = 0; j < 8; ++j) { sa[j] += (float)v0[j]; sb[j] += (float)v1[j]; }
  }
  if (e < end) {
    h8 v0 = H[(size_t)csr_src[e] * 16 + lane];
#pragma unroll
    for (int j = 0; j < 8; ++j) sa[j] += (float)v0[j];
  }
  h8 hv;
#pragma unroll
  for (int j = 0; j < 8; ++j) hv[j] = (_Float16)(sa[j] + sb[j]);
  __builtin_nontemporal_store(hv, &O[(size_t)g * 16 + lane]);
}

// ---- CSR aggregation (64-wide f32, +bout): out = sum z[src] + bout ---------
__global__ __launch_bounds__(THREADS)
void k_agg_z(const float4* __restrict__ Z, const int* __restrict__ row_ptr,
             const int* __restrict__ csr_src, const float* __restrict__ bo,
             float4* __restrict__ Out, int N) {
  int g = blockIdx.x * (THREADS / 16) + (threadIdx.x >> 4);
  int lane = threadIdx.x & 15;
  if (g >= N) return;
  int e = row_ptr[g], end = row_ptr[g + 1];
  float4 sa = ((const float4*)bo)[lane];
  float4 sb = make_float4(0.f, 0.f, 0.f, 0.f);
  for (; e + 3 < end; e += 4) {
    int n0 = csr_src[e], n1 = csr_src[e + 1], n2 = csr_src[e + 2], n3 = csr_src[e + 3];
    float4 v0 = Z[(size_t)n0 * 16 + lane];
    float4 v1 = Z[(size_t)n1 * 16 + lane];
    float4 v2 = Z[(size_t)n2 * 16 + lane];
    float4 v3 = Z[(size_t)n3 * 16 + lane];
    sa = f4_add(v0, sa); sb = f4_add(v1, sb);
    sa = f4_add(v2, sa); sb = f4_add(v3, sb);
  }
  for (; e < end; ++e) sa = f4_add(Z[(size_t)csr_src[e] * 16 + lane], sa);
  float4 s = f4_add(sa, sb);
  nt_store_f4(s, &Out[(size_t)g * 16 + lane]);
}

// ---- MFMA GEMM (layer): H = relu((A@W)*invi + b); emits fp16 H (and H*invo)
// A fp16 [N][128] row-major; W f32 [128][128] row-major (cast to fp16 LDS).
// Block: 128 rows, 4 waves; wave w -> rows w*32..w*32+31 (2 row-tiles x 8
// col-tiles x 4 k-steps of mfma_f32_16x16x32_f16).
template <bool EMIT_S>
__global__ __launch_bounds__(THREADS, 2)
void k_gemm_mfma(const h8* __restrict__ Ah, const float* __restrict__ W,
                 const float* __restrict__ bias, const float* __restrict__ invi,
                 const float* __restrict__ invo,
                 _Float16* __restrict__ Hs, _Float16* __restrict__ Hh, int N) {
  __shared__ _Float16 As[128 * 136];   // [row][k], 272B row stride (17x16B)
  __shared__ _Float16 Ws[128 * 136];   // [col][k] (transposed)
  int t = threadIdx.x;
  int row0 = blockIdx.x * 128;

  {  // stage A: thread -> half-row (64 halfs = 8 x h8)
    int r = t >> 1, hf = t & 1;
    int gr = row0 + r;
    const h8* Arow = Ah + (size_t)gr * 16 + hf * 8;
    h8 z8 = {};
#pragma unroll
    for (int q = 0; q < 8; ++q) {
      h8 v = (gr < N) ? Arow[q] : z8;
      *(h8*)&As[r * 136 + hf * 64 + q * 8] = v;
    }
  }
  {  // stage W transposed, f32 -> fp16
    const float4* Wv = (const float4*)W;
    int n4 = t & 31, kb = t >> 5;
#pragma unroll
    for (int p = 0; p < 16; ++p) {
      int k = kb + p * 8;
      float4 w = Wv[(size_t)k * 32 + n4];
      Ws[(n4 * 4 + 0) * 136 + k] = (_Float16)w.x;
      Ws[(n4 * 4 + 1) * 136 + k] = (_Float16)w.y;
      Ws[(n4 * 4 + 2) * 136 + k] = (_Float16)w.z;
      Ws[(n4 * 4 + 3) * 136 + k] = (_Float16)w.w;
    }
  }
  __syncthreads();

  int wave = t >> 6, lane = t & 63;
  int l15 = lane & 15, lhi = lane >> 4;
  int wr0 = wave * 32;

  h8 a[2][4];
#pragma unroll
  for (int rt = 0; rt < 2; ++rt)
#pragma unroll
    for (int kk = 0; kk < 4; ++kk)
      a[rt][kk] = *(const h8*)&As[(wr0 + rt * 16 + l15) * 136 + kk * 32 + lhi * 8];

  f32x4 acc[2][8] = {};
#pragma unroll
  for (int ct = 0; ct < 8; ++ct) {
    h8 b[4];
#pragma unroll
    for (int kk = 0; kk < 4; ++kk)
      b[kk] = *(const h8*)&Ws[(ct * 16 + l15) * 136 + kk * 32 + lhi * 8];
#pragma unroll
    for (int kk = 0; kk < 4; ++kk) {
      acc[0][ct] = __builtin_amdgcn_mfma_f32_16x16x32_f16(a[0][kk], b[kk], acc[0][ct], 0, 0, 0);
      acc[1][ct] = __builtin_amdgcn_mfma_f32_16x16x32_f16(a[1][kk], b[kk], acc[1][ct], 0, 0, 0);
    }
  }

  float bn[8];
#pragma unroll
  for (int ct = 0; ct < 8; ++ct) bn[ct] = bias[ct * 16 + l15];
#pragma unroll
  for (int rt = 0; rt < 2; ++rt) {
#pragma unroll
    for (int reg = 0; reg < 4; ++reg) {
      int m = row0 + wr0 + rt * 16 + lhi * 4 + reg;
      if (m < N) {
        float si = invi[m];
        float so = EMIT_S ? invo[m] : 0.f;
#pragma unroll
        for (int ct = 0; ct < 8; ++ct) {
          int n = ct * 16 + l15;
          float o = fmaxf(acc[rt][ct][reg] * si + bn[ct], 0.f);
          Hh[(size_t)m * 128 + n] = (_Float16)o;
          if (EMIT_S) Hs[(size_t)m * 128 + n] = (_Float16)(o * so);
        }
      }
    }
  }
}

// ---- MFMA z GEMM: Z = H1@Wo[0:128] + H2@Wo[128:256] (f32 out, N x 64) ------
__global__ __launch_bounds__(THREADS, 2)
void k_gemm_z(const h8* __restrict__ H1, const h8* __restrict__ H2,
              const float* __restrict__ Wo, float* __restrict__ Z, int N) {
  __shared__ _Float16 As[128 * 136];   // [row][k]
  __shared__ _Float16 Ws[64 * 136];    // [col][k]
  int t = threadIdx.x;
  int row0 = blockIdx.x * 128;
  int wave = t >> 6, lane = t & 63;
  int l15 = lane & 15, lhi = lane >> 4;
  int wr0 = wave * 32;

  f32x4 acc[2][4] = {};
#pragma unroll 1
  for (int hf = 0; hf < 2; ++hf) {
    if (hf) __syncthreads();           // all reads of As/Ws done
    {
      int r = t >> 1, rh = t & 1;
      int gr = row0 + r;
      const h8* Asrc = (hf ? H2 : H1) + (size_t)gr * 16 + rh * 8;
      h8 z8 = {};
#pragma unroll
      for (int q = 0; q < 8; ++q) {
        h8 v = (gr < N) ? Asrc[q] : z8;
        *(h8*)&As[r * 136 + rh * 64 + q * 8] = v;
      }
    }
    {
      const float4* Wv = (const float4*)Wo;
      int n4 = t & 15, kb = t >> 4;
#pragma unroll
      for (int p = 0; p < 8; ++p) {
        int k = kb + p * 16;
        float4 w = Wv[(size_t)(hf * 128 + k) * 16 + n4];
        Ws[(n4 * 4 + 0) * 136 + k] = (_Float16)w.x;
        Ws[(n4 * 4 + 1) * 136 + k] = (_Float16)w.y;
        Ws[(n4 * 4 + 2) * 136 + k] = (_Float16)w.z;
        Ws[(n4 * 4 + 3) * 136 + k] = (_Float16)w.w;
      }
    }
    __syncthreads();

    h8 a[2][4];
#pragma unroll
    for (int rt = 0; rt < 2; ++rt)
#pragma unroll
      for (int kk = 0; kk < 4; ++kk)
        a[rt][kk] = *(const h8*)&As[(wr0 + rt * 16 + l15) * 136 + kk * 32 + lhi * 8];
#pragma unroll
    for (int ct = 0; ct < 4; ++ct) {
      h8 b[4];
#pragma unroll
      for (int kk = 0; kk < 4; ++kk)
        b[kk] = *(const h8*)&Ws[(ct * 16 + l15) * 136 + kk * 32 + lhi * 8];
#pragma unroll
      for (int kk = 0; kk < 4; ++kk) {
        acc[0][ct] = __builtin_amdgcn_mfma_f32_16x16x32_f16(a[0][kk], b[kk], acc[0][ct], 0, 0, 0);
        acc[1][ct] = __builtin_amdgcn_mfma_f32_16x16x32_f16(a[1][kk], b[kk], acc[1][ct], 0, 0, 0);
      }
    }
  }

#pragma unroll
  for (int rt = 0; rt < 2; ++rt) {
#pragma unroll
    for (int reg = 0; reg < 4; ++reg) {
      int m = row0 + wr0 + rt * 16 + lhi * 4 + reg;
      if (m < N) {
#pragma unroll
        for (int ct = 0; ct < 4; ++ct) {
          int n = ct * 16 + l15;
          Z[(size_t)m * 64 + n] = acc[rt][ct][reg];
        }
      }
    }
  }
}

// ---------------------------------------------------------------------------
extern "C" void kernel_launch(void* const* d_in, const int* in_sizes, int n_in,
                              void* d_out, int out_size, void* d_ws, size_t ws_size,
                              hipStream_t stream) {
  const float* x    = (const float*)d_in[0];
  const int*   src  = (const int*)d_in[1];
  const int*   dst  = (const int*)d_in[2];
  const float* W1   = (const float*)d_in[3];
  const float* b1   = (const float*)d_in[4];
  const float* W2   = (const float*)d_in[5];
  const float* b2   = (const float*)d_in[6];
  const float* Wout = (const float*)d_in[7];
  const float* bout = (const float*)d_in[8];
  float* out = (float*)d_out;

  const int IN = 128;
  const int N = in_sizes[0] / IN;   // 100000
  const int E = in_sizes[1];        // 1600000
  const int ranges = (N + RANGE - 1) / RANGE;  // 4

  char* p = (char*)d_ws;
  auto alloc = [&](size_t bytes) -> char* {
    char* r = p;
    p += (bytes + 255) & ~(size_t)255;
    return r;
  };
  float* bufz  = (float*)alloc((size_t)2 * CHUNKS * N * 4); // histD|histS, later z (f32 Nx64)
  h8* bX = (h8*)alloc((size_t)N * 128 * 2);  // xs, then aggB
  h8* bA = (h8*)alloc((size_t)N * 128 * 2);  // aggA, then h2h
  h8* bS = (h8*)alloc((size_t)N * 128 * 2);  // h1s
  h8* bH = (h8*)alloc((size_t)N * 128 * 2);  // h1h
  float* invo   = (float*)alloc((size_t)N * 4);
  float* invi   = (float*)alloc((size_t)N * 4);
  int* deg_i    = (int*)alloc((size_t)N * 4);
  int* row_ptr  = (int*)alloc((size_t)(N + 1) * 4);
  int* bsums    = (int*)alloc(1024);
  int* boffs    = (int*)alloc(1024);
  int* csr_src  = (int*)alloc((size_t)E * 4);

  int* histD = (int*)bufz;                       // [CHUNKS][N]
  int* histS = histD + (size_t)CHUNKS * N;       // [CHUNKS][N]

  // ---- CSR build: no global atomics ---------------------------------------
  k_hist<<<ranges * CHUNKS * 2, THREADS, 0, stream>>>(dst, src, histD, histS, N, E, ranges);
  k_redinv<<<(N + THREADS - 1) / THREADS, THREADS, 0, stream>>>(histD, histS, deg_i, invi, invo, N);
  int nb1 = (N + 1023) / 1024;
  k_scan1<<<nb1, THREADS, 0, stream>>>(deg_i, row_ptr, bsums, N);
  k_scan2<<<1, 256, 0, stream>>>(bsums, boffs, nb1);
  k_scan3<<<(N + THREADS - 1) / THREADS, THREADS, 0, stream>>>(row_ptr, deg_i, boffs, N, E);
  k_chunkscan<<<(N + THREADS - 1) / THREADS, THREADS, 0, stream>>>(histD, row_ptr, N);
  k_csr<<<ranges * CHUNKS, THREADS, 0, stream>>>(dst, src, histD, csr_src, N, E, ranges);

  const int aggGrid  = (N + (THREADS / 16) - 1) / (THREADS / 16);
  const int gemmGrid = (N + 127) / 128;
  const int castGrid = (N * 16 + THREADS - 1) / THREADS;

  // ---- layer 1 -------------------------------------------------------------
  k_cast_scale<<<castGrid, THREADS, 0, stream>>>((const float4*)x, invo, bX, N);
  k_agg_h<<<aggGrid, THREADS, 0, stream>>>(bX, row_ptr, csr_src, bA, N);        // aggA
  k_gemm_mfma<true><<<gemmGrid, THREADS, 0, stream>>>(bA, W1, b1, invi, invo,
                                                      (_Float16*)bS, (_Float16*)bH, N);

  // ---- layer 2 -------------------------------------------------------------
  k_agg_h<<<aggGrid, THREADS, 0, stream>>>(bS, row_ptr, csr_src, bX, N);        // aggB (xs dead)
  k_gemm_mfma<false><<<gemmGrid, THREADS, 0, stream>>>(bX, W2, b2, invi, invo,
                                                       nullptr, (_Float16*)bA, N);  // h2h

  // ---- z = h1h@Wo1 + h2h@Wo2 then out = A@z + bout -------------------------
  k_gemm_z<<<gemmGrid, THREADS, 0, stream>>>(bH, bA, Wout, bufz, N);
  k_agg_z<<<aggGrid, THREADS, 0, stream>>>((const float4*)bufz, row_ptr, csr_src,
                                           bout, (float4*)out, N);
}